// Round 16
// baseline (181.678 us; speedup 1.0000x reference)
//
#include <hip/hip_runtime.h>

// Problem constants (fixed by setup_inputs) — float inputs are FP32.
#define NB 8
#define NN 4096
#define DEG 16
#define UN 128
#define NE (NN*DEG)
#define SC 1.2304489f   // fp32(log(17)/log(10))

typedef unsigned short u16;
typedef __attribute__((ext_vector_type(8))) short short8;  // 8 bf16 = 4 VGPRs
typedef __attribute__((ext_vector_type(4))) float f32x4;

__device__ __forceinline__ float b2f(u16 v) { return __uint_as_float(((unsigned)v) << 16); }
// round-to-nearest-even fp32 -> bf16
__device__ __forceinline__ u16 f2b(float f) {
    unsigned u = __float_as_uint(f);
    unsigned r = ((u >> 16) & 1u) + 0x7FFFu;
    return (u16)((u + r) >> 16);
}

// async global->LDS, 16 B per lane, LDS dst = wave-uniform base + lane*16
#define GLLDS16(GP, LP) \
    __builtin_amdgcn_global_load_lds((const __attribute__((address_space(1))) unsigned*)(GP), \
                                     (__attribute__((address_space(3))) unsigned*)(LP), 16, 0, 0)
#define WAIT_VM0() __builtin_amdgcn_s_waitcnt(0x0F70)   // vmcnt(0), exp/lgkm unaffected

// ---------------------------------------------------------------------------
// Prep. blocks 0..383: fold W -> transposed bf16 B-mats + BN consts + zero
// counters. blocks 384..895: pack edge dst column -> u16 dsts[] (coalesced).
// grid 896, block 256.
// ---------------------------------------------------------------------------
__global__ void pna16_prep(const float* W, const float* bias, const float* gamma,
                           const float* beta, const float* mmean, const float* mvar,
                           const int* eidx,
                           u16* AsumT, u16* AmaxT, float* biasf, float* kv, float* cv,
                           u16* dsts, int* counters) {
    const int bid = blockIdx.x;
    const int t = threadIdx.x;  // 256
    if (bid == 0 && t < 16) counters[t] = 0;
    if (bid < 384) {
        if (t < 128) {
            const int d = bid >> 7;
            const int j = bid & 127;
            const int u = t;
            const float* Wd = W + (size_t)d * 9 * UN * UN;
            float w[9];
#pragma unroll
            for (int r = 0; r < 9; r++) w[r] = Wd[(size_t)(r * UN + j) * UN + u];
            float asum = (w[0] + SC * (w[1] + w[2])) * 0.0625f + w[6] + SC * (w[7] + w[8]);
            float amax = w[3] + SC * (w[4] + w[5]);
            AsumT[((size_t)d * UN + u) * UN + j] = f2b(asum);
            AmaxT[((size_t)d * UN + u) * UN + j] = f2b(amax);
            if (j == 0) {
                float k = gamma[d * UN + u] * rsqrtf(mvar[d * UN + u] + 1e-3f);
                kv[d * UN + u] = k;
                cv[d * UN + u] = beta[d * UN + u] - mmean[d * UN + u] * k;
                biasf[d * UN + u] = bias[d * UN + u];
            }
        }
        return;
    }
    const size_t ge = (size_t)(bid - 384) * 1024 + (size_t)t * 4;
    int4 a = *(const int4*)(eidx + 2 * ge);
    int4 c = *(const int4*)(eidx + 2 * ge + 4);
    u16 o[4] = { (u16)(a.y & (NN - 1)), (u16)(a.w & (NN - 1)),
                 (u16)(c.y & (NN - 1)), (u16)(c.w & (NN - 1)) };
    *(uint2*)(dsts + ge) = *(const uint2*)o;
}

// ---------------------------------------------------------------------------
// PNA layer with ASYNC-STAGED gather (global_load_lds). grid 1024 (b = bid&7
// XCD-pin, 32-node tile), block 256, __launch_bounds__(256,4): 4 blocks/CU
// co-resident (r11 lesson). ~36 KB LDS.
// Gather: wave w stages node nl's 16 edge-rows into stage[w] via 4 (bf16) or
// 2x4 (fp32) fire-and-forget global_load_lds_dwordx4, ONE vmcnt(0) drain,
// then conflict-free LDS reduce (lane -> 2 feats). 16 cache lines guaranteed
// in flight per wave; zero VGPR cost (r15 lesson: compiler re-batches VGPR
// loads, cannot re-batch async DMA).
// MODE 0: fp32 x in -> bf16 out; MODE 1: bf16 -> bf16;
// MODE 2: bf16 in -> fused per-tile node-sum; last block per batch runs MLP.
// ---------------------------------------------------------------------------
template <int MODE>
__global__ __launch_bounds__(256, 4) void pna16_layer(
        const void* __restrict__ xin_v, const u16* __restrict__ dsts,
        const u16* __restrict__ AsumT, const u16* __restrict__ AmaxT,
        const float* __restrict__ biasf, const float* __restrict__ kv,
        const float* __restrict__ cv,
        u16* __restrict__ xout, float* __restrict__ partial,
        int* __restrict__ counters,
        const float* __restrict__ Wp1, const float* __restrict__ bp1,
        const float* __restrict__ Wp2, const float* __restrict__ bp2,
        float* __restrict__ out, int d) {
    const int bid = blockIdx.x;
    const int b = bid & 7;               // batch -> XCD pin
    const int tile = bid >> 3;           // 0..127
    const int node0 = tile * 32;
    const int t = threadIdx.x;           // 256
    const int w = t >> 6, lane = t & 63;
    const int l15 = lane & 15, quad = lane >> 4;

    __shared__ u16 sS[32][136];          // s_sum bf16 (row stride 272 B)
    __shared__ u16 sM[32][136];          // s_max bf16
    __shared__ u16 sidx[32 * DEG];       // 512 packed dst indices (1 KB)
    __shared__ unsigned stageU[4][1024]; // 4 KB per-wave async stage
    __shared__ float gmean_s[UN];
    __shared__ float mlp1[UN];
    __shared__ int is_last;

    // coalesced 1 KB index stage
    ((unsigned*)sidx)[t] = ((const unsigned*)(dsts + (size_t)b * NE + (size_t)node0 * DEG))[t];
    __syncthreads();

    // ---- gather-aggregate: wave w handles nodes w*8 .. w*8+7 ----
    if (MODE == 0) {
        const char* xb = (const char*)xin_v + (size_t)b * NN * UN * 4;
        for (int nn = 0; nn < 8; nn++) {
            const int nl = w * 8 + nn;
            float s0 = 0.f, s1 = 0.f, m0 = -1e30f, m1 = -1e30f;
#pragma unroll
            for (int h = 0; h < 2; h++) {
                // stage rows h*8 .. h*8+7 (fp32 rows, 512 B each; 2 rows/instr)
#pragma unroll
                for (int i = 0; i < 4; i++) {
                    int r = h * 8 + i * 2 + (lane >> 5);
                    int dn = sidx[nl * DEG + r];
                    const char* gp = xb + (size_t)dn * 512 + (lane & 31) * 16;
                    GLLDS16(gp, &stageU[w][i * 256]);
                }
                WAIT_VM0();
#pragma unroll
                for (int e = 0; e < 8; e++) {
                    float2 v = *(const float2*)&stageU[w][e * 128 + lane * 2];
                    s0 += v.x; s1 += v.y;
                    m0 = fmaxf(m0, v.x); m1 = fmaxf(m1, v.y);
                }
            }
            *(unsigned*)&sS[nl][lane * 2] = (unsigned)f2b(s0) | ((unsigned)f2b(s1) << 16);
            *(unsigned*)&sM[nl][lane * 2] = (unsigned)f2b(m0) | ((unsigned)f2b(m1) << 16);
        }
    } else {
        const char* xb = (const char*)xin_v + (size_t)b * NN * UN * 2;
        for (int nn = 0; nn < 8; nn++) {
            const int nl = w * 8 + nn;
            // stage all 16 rows (bf16 rows, 256 B each; 4 rows/instr)
#pragma unroll
            for (int i = 0; i < 4; i++) {
                int r = i * 4 + (lane >> 4);
                int dn = sidx[nl * DEG + r];
                const char* gp = xb + (size_t)dn * 256 + (lane & 15) * 16;
                GLLDS16(gp, &stageU[w][i * 256]);
            }
            WAIT_VM0();
            float s0 = 0.f, s1 = 0.f, m0 = -1e30f, m1 = -1e30f;
#pragma unroll
            for (int e = 0; e < 16; e++) {
                unsigned v = stageU[w][e * 64 + lane];
                float lo = __uint_as_float(v << 16);
                float hi = __uint_as_float(v & 0xffff0000u);
                s0 += lo; s1 += hi;
                m0 = fmaxf(m0, lo); m1 = fmaxf(m1, hi);
            }
            *(unsigned*)&sS[nl][lane * 2] = (unsigned)f2b(s0) | ((unsigned)f2b(s1) << 16);
            *(unsigned*)&sM[nl][lane * 2] = (unsigned)f2b(m0) | ((unsigned)f2b(m1) << 16);
        }
    }
    __syncthreads();

    // MFMA (r12's proven loop): wave w -> units [w*32,+32), m-subtiles 0,1
    const u16* Bs = AsumT + (size_t)d * UN * UN;
    const u16* Bm = AmaxT + (size_t)d * UN * UN;
    f32x4 acc[2][2] = {};
#pragma unroll
    for (int msub = 0; msub < 2; msub++) {
#pragma unroll
        for (int k0 = 0; k0 < 4; k0++) {
            const int koff = k0 * 32 + quad * 8;
            short8 aS = *(const short8*)(&sS[msub * 16 + l15][koff]);
            short8 aM = *(const short8*)(&sM[msub * 16 + l15][koff]);
#pragma unroll
            for (int nt = 0; nt < 2; nt++) {
                const int ng = w * 2 + nt;
                short8 bS = *(const short8*)(Bs + (size_t)(ng * 16 + l15) * UN + koff);
                short8 bM = *(const short8*)(Bm + (size_t)(ng * 16 + l15) * UN + koff);
                acc[msub][nt] = __builtin_amdgcn_mfma_f32_16x16x32_bf16(aS, bS, acc[msub][nt], 0, 0, 0);
                acc[msub][nt] = __builtin_amdgcn_mfma_f32_16x16x32_bf16(aM, bM, acc[msub][nt], 0, 0, 0);
            }
        }
    }

    if (MODE < 2) {
        // epilogue: y = relu(acc+bias)*k + c -> bf16 via LDS staging.
        // C-map: node = msub*16 + quad*4 + r, unit = ng*16 + l15.
        __syncthreads();
#pragma unroll
        for (int nt = 0; nt < 2; nt++) {
            const int u = (w * 2 + nt) * 16 + l15;
            const float bb = biasf[d * UN + u], kk = kv[d * UN + u], cc = cv[d * UN + u];
#pragma unroll
            for (int msub = 0; msub < 2; msub++)
#pragma unroll
                for (int r = 0; r < 4; r++) {
                    float y = fmaxf(acc[msub][nt][r] + bb, 0.0f) * kk + cc;
                    sS[msub * 16 + quad * 4 + r][u] = f2b(y);
                }
        }
        __syncthreads();
#pragma unroll
        for (int p = 0; p < 2; p++) {
            int r = (t >> 4) + p * 16;
            int c0 = (t & 15) * 8;
            *(uint4*)(xout + ((size_t)b * NN + node0 + r) * UN + c0) =
                *(const uint4*)(&sS[r][c0]);
        }
    } else {
        // fused readout stage 1: per-unit sum over tile's 32 nodes
        float* red = (float*)sM;   // [4 quads][128 units] fp32
        __syncthreads();
#pragma unroll
        for (int nt = 0; nt < 2; nt++) {
            const int u = (w * 2 + nt) * 16 + l15;
            const float bb = biasf[d * UN + u], kk = kv[d * UN + u], cc = cv[d * UN + u];
            float s = 0.0f;
#pragma unroll
            for (int msub = 0; msub < 2; msub++)
#pragma unroll
                for (int r = 0; r < 4; r++)
                    s += fmaxf(acc[msub][nt][r] + bb, 0.0f) * kk + cc;
            red[quad * UN + u] = s;
        }
        __syncthreads();
        if (t < UN) {
            float s = red[t] + red[UN + t] + red[2 * UN + t] + red[3 * UN + t];
            partial[((size_t)b * 128 + tile) * UN + t] = s;
        }
        __syncthreads();
        if (t == 0) {
            __threadfence();                       // release partial stores
            int old = atomicAdd(&counters[b], 1);  // device-scope
            is_last = (old == 127);
        }
        __syncthreads();
        if (is_last) {
            __threadfence();                       // acquire other tiles' partials
            {   // parallel gmean: (u, half) over 128 tiles
                const int u = t & 127, half = t >> 7;
                float s = 0.0f;
                for (int c = half * 64; c < half * 64 + 64; c++)
                    s += partial[((size_t)b * 128 + c) * UN + u];
                if (half == 0) gmean_s[u] = s; else mlp1[u] = s;
            }
            __syncthreads();
            if (t < UN)
                gmean_s[t] = (gmean_s[t] + mlp1[t]) * (1.0f / (float)NN);
            __syncthreads();
            if (t < UN) {
                float a = bp1[t];
                for (int j = 0; j < UN; j++)
                    a += gmean_s[j] * Wp1[j * UN + t];
                mlp1[t] = fmaxf(a, 0.0f);
            }
            __syncthreads();
            if (t < 64) {
                float o = bp2[t];
                for (int j = 0; j < UN; j++)
                    o += mlp1[j] * Wp2[j * 64 + t];
                out[b * 64 + t] = fmaxf(o, 0.0f);
            }
        }
    }
}

extern "C" void kernel_launch(void* const* d_in, const int* in_sizes, int n_in,
                              void* d_out, int out_size, void* d_ws, size_t ws_size,
                              hipStream_t stream) {
    const float* xattr = (const float*)d_in[0];   // [8,4096,128] fp32
    const int*   eidx  = (const int*)d_in[1];     // [8,65536,2] int32
    const float* W     = (const float*)d_in[2];   // [3,1152,128] fp32
    const float* bias  = (const float*)d_in[3];
    const float* gamma = (const float*)d_in[4];
    const float* beta  = (const float*)d_in[5];
    const float* mmean = (const float*)d_in[6];
    const float* mvar  = (const float*)d_in[7];
    const float* Wp1   = (const float*)d_in[8];   // [128,128]
    const float* bp1   = (const float*)d_in[9];
    const float* Wp2   = (const float*)d_in[10];  // [128,64]
    const float* bp2   = (const float*)d_in[11];
    float* out = (float*)d_out;                   // [8,64] fp32

    u16* AsumT = (u16*)d_ws;                        // 3*128*128 bf16
    u16* AmaxT = AsumT + 3 * UN * UN;
    float* biasf = (float*)(AmaxT + 3 * UN * UN);   // 3*128 fp32
    float* kv = biasf + 3 * UN;
    float* cv = kv + 3 * UN;
    int* counters = (int*)(cv + 3 * UN);            // 16 ints
    float* partial = (float*)(counters + 16);       // [8,128,128] fp32
    u16* dsts = (u16*)(partial + (size_t)NB * 128 * UN);  // 8*65536 u16
    u16* buf0 = dsts + (size_t)NB * NE;             // [8,4096,128] bf16
    u16* buf1 = buf0 + (size_t)NB * NN * UN;

    pna16_prep<<<896, 256, 0, stream>>>(W, bias, gamma, beta, mmean, mvar, eidx,
                                        AsumT, AmaxT, biasf, kv, cv, dsts, counters);
    pna16_layer<0><<<1024, 256, 0, stream>>>(xattr, dsts, AsumT, AmaxT, biasf, kv, cv,
                                             buf0, partial, counters,
                                             Wp1, bp1, Wp2, bp2, out, 0);
    pna16_layer<1><<<1024, 256, 0, stream>>>(buf0, dsts, AsumT, AmaxT, biasf, kv, cv,
                                             buf1, partial, counters,
                                             Wp1, bp1, Wp2, bp2, out, 1);
    pna16_layer<2><<<1024, 256, 0, stream>>>(buf1, dsts, AsumT, AmaxT, biasf, kv, cv,
                                             (u16*)nullptr, partial, counters,
                                             Wp1, bp1, Wp2, bp2, out, 2);
}